// Round 9
// baseline (2123.891 us; speedup 1.0000x reference)
//
#include <hip/hip_runtime.h>
#include <cstddef>
#include <cstdint>

// Problem constants
#define TT 256
#define BB 64
#define NTAG 34
// M = TT*BB = 16384

// Fast gate nonlinearities on the transcendental pipe via compiler intrinsics
// (__builtin_amdgcn_exp2f -> v_exp_f32, __builtin_amdgcn_rcpf -> v_rcp_f32);
// compiler owns the TRANS-op wait-state insertion.  Verified r5.
__device__ __forceinline__ float sigf(float x) {
  return __builtin_amdgcn_rcpf(1.0f + __builtin_amdgcn_exp2f(-1.442695041f * x));
}
__device__ __forceinline__ float tanh_fast(float x) {
  return 1.0f -
         2.0f * __builtin_amdgcn_rcpf(1.0f + __builtin_amdgcn_exp2f(2.885390082f * x));
}

// DPP butterfly/rotate helpers — full 16-lane reduce on the VALU DPP network,
// zero DS-pipe ops.  Verified r3/r5.
__device__ __forceinline__ float addx1(float v) {
  return v + __int_as_float(
                 __builtin_amdgcn_mov_dpp(__float_as_int(v), 0xB1, 0xF, 0xF, true));
}
__device__ __forceinline__ float addx2(float v) {
  return v + __int_as_float(
                 __builtin_amdgcn_mov_dpp(__float_as_int(v), 0x4E, 0xF, 0xF, true));
}
__device__ __forceinline__ float addror4(float v) {
  return v + __int_as_float(
                 __builtin_amdgcn_mov_dpp(__float_as_int(v), 0x124, 0xF, 0xF, true));
}
__device__ __forceinline__ float addror8(float v) {
  return v + __int_as_float(
                 __builtin_amdgcn_mov_dpp(__float_as_int(v), 0x128, 0xF, 0xF, true));
}

// ---------------------------------------------------------------------------
// fp32 tiled GEMM v5-clean: v4 + 1-deep REGISTER PIPELINE of LDS fragments
// (prefetch k+1's 4x float4 while k's 64 FMAs retire), WITHOUT the r7
// launch-bounds rider that poisoned the first attempt (allocator clamped to
// VGPR=64 < the 64-float accumulator -> scratch spill -> 6GB/dispatch).
// Occupancy math: VGPR 104->~120 stays under the 128-VGPR step (4 waves/SIMD
// unchanged); LDS 33.8KB independently caps 4 blocks/CU.  Same FMA order and
// addresses — bit-identical results.  MUST VERIFY in counters: VGPR<=128,
// FETCH_SIZE stays ~MB-class (no scratch).
// ---------------------------------------------------------------------------
__global__ __launch_bounds__(256) void gemm_k(
    const float* __restrict__ Abase, const int* __restrict__ gidx,
    const float* __restrict__ W, const float* __restrict__ biasA,
    const float* __restrict__ biasB, float* __restrict__ out,
    int M, int K, int Nvalid, int xp_mode) {
  __shared__ float As[2][16][132];
  __shared__ float Bs[2][16][132];
  int tid = threadIdx.x;
  int m0 = blockIdx.x * 128;
  int n0 = blockIdx.y * 128;
  int tx = tid & 15, ty = tid >> 4;
  int srow = tid >> 2;
  int c4 = tid & 3;
  int kb = c4 * 4;

  float acc[8][8];
#pragma unroll
  for (int i = 0; i < 8; ++i)
#pragma unroll
    for (int j = 0; j < 8; ++j) acc[i][j] = 0.0f;

  const float* a0p;
  const float* a1p;
  {
    int ma = m0 + srow, mb = m0 + srow + 64;
    size_t ra = gidx ? (size_t)gidx[ma] : (size_t)ma;
    size_t rb = gidx ? (size_t)gidx[mb] : (size_t)mb;
    a0p = Abase + ra * (size_t)K + c4 * 4;
    a1p = Abase + rb * (size_t)K + c4 * 4;
  }
  int nA = n0 + srow, nB = n0 + srow + 64;
  const float* b0p = W + (size_t)nA * K + c4 * 4;
  const float* b1p = W + (size_t)nB * K + c4 * 4;
  bool v0 = nA < Nvalid, v1 = nB < Nvalid;

  // Prologue: stage tile 0
  {
    float4 a0 = *(const float4*)(a0p);
    float4 a1 = *(const float4*)(a1p);
    float4 b0 = v0 ? *(const float4*)(b0p) : make_float4(0, 0, 0, 0);
    float4 b1 = v1 ? *(const float4*)(b1p) : make_float4(0, 0, 0, 0);
    As[0][kb + 0][srow] = a0.x; As[0][kb + 1][srow] = a0.y;
    As[0][kb + 2][srow] = a0.z; As[0][kb + 3][srow] = a0.w;
    As[0][kb + 0][srow + 64] = a1.x; As[0][kb + 1][srow + 64] = a1.y;
    As[0][kb + 2][srow + 64] = a1.z; As[0][kb + 3][srow + 64] = a1.w;
    Bs[0][kb + 0][srow] = b0.x; Bs[0][kb + 1][srow] = b0.y;
    Bs[0][kb + 2][srow] = b0.z; Bs[0][kb + 3][srow] = b0.w;
    Bs[0][kb + 0][srow + 64] = b1.x; Bs[0][kb + 1][srow + 64] = b1.y;
    Bs[0][kb + 2][srow + 64] = b1.z; Bs[0][kb + 3][srow + 64] = b1.w;
  }
  __syncthreads();

  int cur = 0;
  for (int k0 = 0; k0 < K; k0 += 16) {
    bool more = (k0 + 16) < K;
    float4 na0, na1, nb0, nb1;
    if (more) {  // issue next-tile global loads; they fly during the FMA block
      na0 = *(const float4*)(a0p + k0 + 16);
      na1 = *(const float4*)(a1p + k0 + 16);
      nb0 = v0 ? *(const float4*)(b0p + k0 + 16) : make_float4(0, 0, 0, 0);
      nb1 = v1 ? *(const float4*)(b1p + k0 + 16) : make_float4(0, 0, 0, 0);
    }
    // Fragment register pipeline: load k=0, prefetch k+1 during k's FMAs.
    float4 av0 = *(const float4*)&As[cur][0][ty * 4];
    float4 av1 = *(const float4*)&As[cur][0][ty * 4 + 64];
    float4 bv0 = *(const float4*)&Bs[cur][0][tx * 4];
    float4 bv1 = *(const float4*)&Bs[cur][0][tx * 4 + 64];
#pragma unroll
    for (int k = 0; k < 16; ++k) {
      float a[8] = {av0.x, av0.y, av0.z, av0.w, av1.x, av1.y, av1.z, av1.w};
      float b[8] = {bv0.x, bv0.y, bv0.z, bv0.w, bv1.x, bv1.y, bv1.z, bv1.w};
      if (k < 15) {
        av0 = *(const float4*)&As[cur][k + 1][ty * 4];       // 2-way: free
        av1 = *(const float4*)&As[cur][k + 1][ty * 4 + 64];
        bv0 = *(const float4*)&Bs[cur][k + 1][tx * 4];
        bv1 = *(const float4*)&Bs[cur][k + 1][tx * 4 + 64];
      }
#pragma unroll
      for (int i = 0; i < 8; ++i)
#pragma unroll
        for (int j = 0; j < 8; ++j) acc[i][j] += a[i] * b[j];
    }
    if (more) {
      int nxt = cur ^ 1;  // write other buffer: no race with cur's readers
      As[nxt][kb + 0][srow] = na0.x; As[nxt][kb + 1][srow] = na0.y;
      As[nxt][kb + 2][srow] = na0.z; As[nxt][kb + 3][srow] = na0.w;
      As[nxt][kb + 0][srow + 64] = na1.x; As[nxt][kb + 1][srow + 64] = na1.y;
      As[nxt][kb + 2][srow + 64] = na1.z; As[nxt][kb + 3][srow + 64] = na1.w;
      Bs[nxt][kb + 0][srow] = nb0.x; Bs[nxt][kb + 1][srow] = nb0.y;
      Bs[nxt][kb + 2][srow] = nb0.z; Bs[nxt][kb + 3][srow] = nb0.w;
      Bs[nxt][kb + 0][srow + 64] = nb1.x; Bs[nxt][kb + 1][srow + 64] = nb1.y;
      Bs[nxt][kb + 2][srow + 64] = nb1.z; Bs[nxt][kb + 3][srow + 64] = nb1.w;
      __syncthreads();  // the only barrier per iteration
      cur = nxt;
    }
  }

  // Epilogue (split-fragment row/col mapping)
  float bsum[8];
#pragma unroll
  for (int j = 0; j < 8; ++j) {
    int n = n0 + (j < 4 ? tx * 4 + j : 64 + tx * 4 + (j - 4));
    bsum[j] = (n < Nvalid) ? (biasA[n] + (biasB ? biasB[n] : 0.0f)) : 0.0f;
  }
  if (xp_mode) {
    int dir = n0 >> 10;
    int nlo = (n0 & 1023) + tx * 4;
#pragma unroll
    for (int i = 0; i < 8; ++i) {
      int m = m0 + (i < 4 ? ty * 4 + i : 64 + ty * 4 + (i - 4));
      float* orow = out + ((size_t)dir * M + m) * 1024 + nlo;
      float4 r0 = make_float4(acc[i][0] + bsum[0], acc[i][1] + bsum[1],
                              acc[i][2] + bsum[2], acc[i][3] + bsum[3]);
      float4 r1 = make_float4(acc[i][4] + bsum[4], acc[i][5] + bsum[5],
                              acc[i][6] + bsum[6], acc[i][7] + bsum[7]);
      *(float4*)(orow) = r0;
      *(float4*)(orow + 64) = r1;
    }
  } else {
#pragma unroll
    for (int i = 0; i < 8; ++i) {
      int m = m0 + (i < 4 ? ty * 4 + i : 64 + ty * 4 + (i - 4));
#pragma unroll
      for (int j = 0; j < 8; ++j) {
        int n = n0 + (j < 4 ? tx * 4 + j : 64 + tx * 4 + (j - 4));
        if (n < Nvalid) out[(size_t)m * Nvalid + n] = acc[i][j] + bsum[j];
      }
    }
  }
}

// ---------------------------------------------------------------------------
// Register-stationary LSTM recurrence, v3.4b — EXACT r5/r8-verified state
// (~684us/dispatch).  Two barriers per step, single-buffer hS/xgS, simple
// spin, x-load at loop top (overlaps the spin — r6 proved moving it
// REGRESSES +40us).  Full-VALU DPP reduce + trans-pipe gates.
// DO NOT PERTURB: structure is at its exchange-latency floor (r6 evidence).
// ---------------------------------------------------------------------------
__global__ __launch_bounds__(512) void lstm_fused3(
    const float* __restrict__ xp,    // [2][M][1024]
    const float* __restrict__ whh,   // [2][1024][256]
    const int* __restrict__ lengths,
    float* __restrict__ out,         // [M][512]
    unsigned long long* hx,          // [2 slot][2 d][16 bg][1024 packets]
    int T, int B) {
  __shared__ float4 hS[256];
  __shared__ float xgS[512];
  int blk = blockIdx.x;
  int js = blk >> 5;
  int inner = blk & 31;
  int d = inner >> 4;
  int bg = inner & 15;
  int tid = threadIdx.x;
  int jl = tid >> 4, kseg = tid & 15;
  int j = js * 32 + jl;
  size_t M = (size_t)T * B;
  int b0 = bg * 4;

  float w[4][16];
#pragma unroll
  for (int g = 0; g < 4; ++g) {
    const float* wr = whh + ((size_t)d * 1024 + g * 256 + j) * 256 + kseg;
#pragma unroll
    for (int i = 0; i < 16; ++i) w[g][i] = wr[16 * i];
  }

  int batch = b0 + (kseg & 3);
  int len = lengths[batch];
  float cst = 0.0f, hst = 0.0f;

  unsigned long long* hx_grp = hx + ((size_t)d * 16 + bg) * 1024;
  const size_t slotStride = (size_t)2 * 16 * 1024;

  int lb = tid >> 7, lg = (tid >> 5) & 3, lj = tid & 31;
  const float* xg_base = xp + (size_t)d * M * 1024 + (size_t)lg * 256 + js * 32 + lj;

  for (int s = 0; s < T; ++s) {
    int t = d ? (T - 1 - s) : s;
    float xv = xg_base[((size_t)t * B + b0 + lb) * 1024];
    if (s == 0) {
      if (tid < 256) hS[tid] = make_float4(0.f, 0.f, 0.f, 0.f);
    } else {
      const unsigned long long* src = hx_grp + (size_t)(s & 1) * slotStride;
      unsigned int want = (unsigned int)s;
      unsigned long long p0, p1;
      int guard = 0;
      for (;;) {
        p0 = __hip_atomic_load(src + tid, __ATOMIC_RELAXED, __HIP_MEMORY_SCOPE_AGENT);
        p1 = __hip_atomic_load(src + 512 + tid, __ATOMIC_RELAXED, __HIP_MEMORY_SCOPE_AGENT);
        if ((unsigned int)(p0 >> 32) == want && (unsigned int)(p1 >> 32) == want)
          break;
        if (++guard > (1 << 22)) break;  // hang-preventer
      }
      ((float*)hS)[tid] = __uint_as_float((unsigned int)p0);
      ((float*)hS)[512 + tid] = __uint_as_float((unsigned int)p1);
    }
    xgS[tid] = xv;
    __syncthreads();

    float acc[4][4];
#pragma unroll
    for (int g = 0; g < 4; ++g)
#pragma unroll
      for (int b = 0; b < 4; ++b) acc[g][b] = 0.0f;
#pragma unroll
    for (int i = 0; i < 16; ++i) {
      float4 hv = hS[kseg + 16 * i];
#pragma unroll
      for (int g = 0; g < 4; ++g) {
        acc[g][0] += w[g][i] * hv.x;
        acc[g][1] += w[g][i] * hv.y;
        acc[g][2] += w[g][i] * hv.z;
        acc[g][3] += w[g][i] * hv.w;
      }
    }
#pragma unroll
    for (int g = 0; g < 4; ++g)
#pragma unroll
      for (int b = 0; b < 4; ++b) {
        float v = acc[g][b];
        v = addx1(v);              // xor1 via DPP quad_perm
        v = addx2(v);              // xor2 via DPP quad_perm
        v = addror4(v);            // cross-quad stage 1 via DPP row_ror:4
        v = addror8(v);            // cross-quad stage 2 via DPP row_ror:8
        acc[g][b] = v;
      }

    if (kseg < 4) {
      int b = kseg;
      float ig = sigf(acc[0][b] + xgS[b * 128 + 0 * 32 + jl]);
      float fg = sigf(acc[1][b] + xgS[b * 128 + 1 * 32 + jl]);
      float gg = tanh_fast(acc[2][b] + xgS[b * 128 + 2 * 32 + jl]);
      float og = sigf(acc[3][b] + xgS[b * 128 + 3 * 32 + jl]);
      bool m = t < len;
      float cn = fg * cst + ig * gg;
      float hn = og * tanh_fast(cn);
      if (m) { cst = cn; hst = hn; }
      if (s + 1 < T) {
        unsigned long long pkt =
            ((unsigned long long)(unsigned int)(s + 1) << 32) | __float_as_uint(hst);
        unsigned long long* dst = hx_grp + (size_t)((s + 1) & 1) * slotStride +
                                  (size_t)js * 128 + jl * 4 + b;
        __hip_atomic_store(dst, pkt, __ATOMIC_RELAXED, __HIP_MEMORY_SCOPE_AGENT);
      }
      out[((size_t)t * B + batch) * 512 + d * 256 + j] = m ? hst : 0.0f;
    }
    __syncthreads();
  }
}

// ---------------------------------------------------------------------------
// Viterbi v4 (verified r5/r8): register trans column + even/odd dual-chain
// max with exact first-occurrence tie-break; LDS u8 hist backtrace. UNCHANGED.
// ---------------------------------------------------------------------------
__global__ __launch_bounds__(64) void viterbi_k(
    const float* __restrict__ em, const int* __restrict__ lengths,
    const float* __restrict__ startT, const float* __restrict__ endT,
    const float* __restrict__ trans,
    int* __restrict__ outTags, int T, int B) {
  __shared__ float sc[NTAG];
  __shared__ float ns[NTAG];
  __shared__ unsigned char histS[TT][NTAG];
  int b = blockIdx.x;
  int j = threadIdx.x;
  int len = lengths[b];
  float trc[NTAG];
  if (j < NTAG) {
#pragma unroll
    for (int i = 0; i < NTAG; ++i) trc[i] = trans[i * NTAG + j];
    sc[j] = startT[j] + em[(size_t)b * NTAG + j];
  }
  __syncthreads();
  for (int t = 1; t < T; ++t) {
    if (j < NTAG) {
      // two independent chains (even i / odd i), combined with first-
      // occurrence tie-break: winner by value, then by smaller index.
      float be = -3.0e38f, bo = -3.0e38f;
      int ae = 0, ao = 1;
#pragma unroll
      for (int i = 0; i < NTAG; i += 2) {
        float ve = sc[i] + trc[i];
        if (ve > be) { be = ve; ae = i; }
        float vo = sc[i + 1] + trc[i + 1];
        if (vo > bo) { bo = vo; ao = i + 1; }
      }
      float best; int arg;
      if (bo > be || (bo == be && ao < ae)) { best = bo; arg = ao; }
      else { best = be; arg = ae; }
      bool m = t < len;
      float e = em[((size_t)t * B + b) * NTAG + j];
      ns[j] = m ? (best + e) : sc[j];
      histS[t - 1][j] = (unsigned char)(m ? arg : j);
    }
    __syncthreads();
    if (j < NTAG) sc[j] = ns[j];
    __syncthreads();
  }
  if (j == 0) {
    float best = -3.0e38f;
    int arg = 0;
    for (int i = 0; i < NTAG; ++i) {
      float v = sc[i] + endT[i];
      if (v > best) { best = v; arg = i; }
    }
    int tag = arg;
    outTags[(size_t)(T - 1) * B + b] = (T - 1 < len) ? tag : 0;
    for (int t = T - 2; t >= 0; --t) {
      tag = histS[t][tag];
      outTags[(size_t)t * B + b] = (t < len) ? tag : 0;
    }
  }
}

extern "C" void kernel_launch(void* const* d_in, const int* in_sizes, int n_in,
                              void* d_out, int out_size, void* d_ws, size_t ws_size,
                              hipStream_t stream) {
  const int* x = (const int*)d_in[0];
  const int* lens = (const int*)d_in[1];
  const float* embed = (const float*)d_in[2];
  const float* w_ih0 = (const float*)d_in[3];
  const float* w_hh0 = (const float*)d_in[4];
  const float* b_ih0 = (const float*)d_in[5];
  const float* b_hh0 = (const float*)d_in[6];
  const float* w_ih1 = (const float*)d_in[7];
  const float* w_hh1 = (const float*)d_in[8];
  const float* b_ih1 = (const float*)d_in[9];
  const float* b_hh1 = (const float*)d_in[10];
  const float* w_lin = (const float*)d_in[11];
  const float* b_lin = (const float*)d_in[12];
  const float* startT = (const float*)d_in[13];
  const float* endT = (const float*)d_in[14];
  const float* trans = (const float*)d_in[15];
  int* outTags = (int*)d_out;

  const int T = TT, B = BB;
  const int M = T * B;

  char* ws = (char*)d_ws;
  const size_t SZ_XP = 2ull * M * 1024 * 4;
  const size_t SZ_H = (size_t)M * 512 * 4;
  const size_t SZ_EM = (size_t)M * NTAG * 4;
  const size_t SZ_HIST = (size_t)M * NTAG * 4;  // layout kept; hist in LDS
  float* xp = (float*)(ws);
  float* h0 = (float*)(ws + SZ_XP);
  float* h1 = (float*)(ws + SZ_XP + SZ_H);
  float* em = (float*)(ws + SZ_XP + 2 * SZ_H);
  unsigned long long* hx0 = (unsigned long long*)(ws + SZ_XP + 2 * SZ_H + SZ_EM + SZ_HIST);
  unsigned long long* hx1 = hx0 + 2ull * 2 * 16 * 1024;
  // No memset needed: 0xAA poison never matches a stamp value 1..255.

  // 1. Layer-0 input projection (fused embedding gather)
  gemm_k<<<dim3(M / 128, 16), 256, 0, stream>>>(embed, x, w_ih0, b_ih0, b_hh0,
                                                xp, M, 256, 2048, 1);
  // 2. Layer-0 recurrence
  lstm_fused3<<<256, 512, 0, stream>>>(xp, w_hh0, lens, h0, hx0, T, B);

  // 3. Layer-1 input projection
  gemm_k<<<dim3(M / 128, 16), 256, 0, stream>>>(h0, nullptr, w_ih1, b_ih1, b_hh1,
                                                xp, M, 512, 2048, 1);
  // 4. Layer-1 recurrence
  lstm_fused3<<<256, 512, 0, stream>>>(xp, w_hh1, lens, h1, hx1, T, B);

  // 5. Emissions
  gemm_k<<<dim3(M / 128, 1), 256, 0, stream>>>(h1, nullptr, w_lin, b_lin, nullptr,
                                               em, M, 512, 34, 0);
  // 6. Viterbi decode
  viterbi_k<<<64, 64, 0, stream>>>(em, lens, startT, endT, trans, outTags, T, B);
  (void)in_sizes; (void)n_in; (void)out_size; (void)ws_size;
}

// Round 10
// 2090.455 us; speedup vs baseline: 1.0160x; 1.0160x over previous
//
#include <hip/hip_runtime.h>
#include <cstddef>
#include <cstdint>

// Problem constants
#define TT 256
#define BB 64
#define NTAG 34
// M = TT*BB = 16384

// Fast gate nonlinearities on the transcendental pipe via compiler intrinsics
// (__builtin_amdgcn_exp2f -> v_exp_f32, __builtin_amdgcn_rcpf -> v_rcp_f32);
// compiler owns the TRANS-op wait-state insertion.  Verified r5.
__device__ __forceinline__ float sigf(float x) {
  return __builtin_amdgcn_rcpf(1.0f + __builtin_amdgcn_exp2f(-1.442695041f * x));
}
__device__ __forceinline__ float tanh_fast(float x) {
  return 1.0f -
         2.0f * __builtin_amdgcn_rcpf(1.0f + __builtin_amdgcn_exp2f(2.885390082f * x));
}

// DPP butterfly/rotate helpers — full 16-lane reduce on the VALU DPP network,
// zero DS-pipe ops.  Verified r3/r5.
__device__ __forceinline__ float addx1(float v) {
  return v + __int_as_float(
                 __builtin_amdgcn_mov_dpp(__float_as_int(v), 0xB1, 0xF, 0xF, true));
}
__device__ __forceinline__ float addx2(float v) {
  return v + __int_as_float(
                 __builtin_amdgcn_mov_dpp(__float_as_int(v), 0x4E, 0xF, 0xF, true));
}
__device__ __forceinline__ float addror4(float v) {
  return v + __int_as_float(
                 __builtin_amdgcn_mov_dpp(__float_as_int(v), 0x124, 0xF, 0xF, true));
}
__device__ __forceinline__ float addror8(float v) {
  return v + __int_as_float(
                 __builtin_amdgcn_mov_dpp(__float_as_int(v), 0x128, 0xF, 0xF, true));
}

// ---------------------------------------------------------------------------
// fp32 tiled GEMM v4 — EXACT r5/r8-verified state (total 2092/2094us).
// out[m][n] = sum_k A[m][k]*W[n][k] + biasA[n] (+biasB[n]).  BM=BN=128,
// BK=16, 256 threads, 8x8 micro-tile with SPLIT fragments (stride-4 reads ->
// 2-way LDS aliasing = free) + DOUBLE-BUFFERED LDS staging, ONE barrier per
// iteration.
// CLOSED EXPERIMENTS (do not repeat):
//  r7: __launch_bounds__(256,4) rider -> VGPR=64 < 64-float acc -> scratch
//      spill, 6GB/dispatch, 2x regression.  NO launch-bounds riders.
//  r9: clean 1-deep fragment register pipeline (VGPR<=128, no spill) ->
//      +30us total.  Compiler's own lgkmcnt interleave already hides LDS
//      latency; explicit pipelining only lengthens register lifetimes.
// Structural note: ~49% of fp32 peak vs ~66% LDS-BW ceiling (ds_read_b128
// 85/128 B/cy; microtile needs 2.0 FLOP/B = exactly LDS peak).
// ---------------------------------------------------------------------------
__global__ __launch_bounds__(256) void gemm_k(
    const float* __restrict__ Abase, const int* __restrict__ gidx,
    const float* __restrict__ W, const float* __restrict__ biasA,
    const float* __restrict__ biasB, float* __restrict__ out,
    int M, int K, int Nvalid, int xp_mode) {
  __shared__ float As[2][16][132];
  __shared__ float Bs[2][16][132];
  int tid = threadIdx.x;
  int m0 = blockIdx.x * 128;
  int n0 = blockIdx.y * 128;
  int tx = tid & 15, ty = tid >> 4;
  int srow = tid >> 2;
  int c4 = tid & 3;
  int kb = c4 * 4;

  float acc[8][8];
#pragma unroll
  for (int i = 0; i < 8; ++i)
#pragma unroll
    for (int j = 0; j < 8; ++j) acc[i][j] = 0.0f;

  const float* a0p;
  const float* a1p;
  {
    int ma = m0 + srow, mb = m0 + srow + 64;
    size_t ra = gidx ? (size_t)gidx[ma] : (size_t)ma;
    size_t rb = gidx ? (size_t)gidx[mb] : (size_t)mb;
    a0p = Abase + ra * (size_t)K + c4 * 4;
    a1p = Abase + rb * (size_t)K + c4 * 4;
  }
  int nA = n0 + srow, nB = n0 + srow + 64;
  const float* b0p = W + (size_t)nA * K + c4 * 4;
  const float* b1p = W + (size_t)nB * K + c4 * 4;
  bool v0 = nA < Nvalid, v1 = nB < Nvalid;

  // Prologue: stage tile 0
  {
    float4 a0 = *(const float4*)(a0p);
    float4 a1 = *(const float4*)(a1p);
    float4 b0 = v0 ? *(const float4*)(b0p) : make_float4(0, 0, 0, 0);
    float4 b1 = v1 ? *(const float4*)(b1p) : make_float4(0, 0, 0, 0);
    As[0][kb + 0][srow] = a0.x; As[0][kb + 1][srow] = a0.y;
    As[0][kb + 2][srow] = a0.z; As[0][kb + 3][srow] = a0.w;
    As[0][kb + 0][srow + 64] = a1.x; As[0][kb + 1][srow + 64] = a1.y;
    As[0][kb + 2][srow + 64] = a1.z; As[0][kb + 3][srow + 64] = a1.w;
    Bs[0][kb + 0][srow] = b0.x; Bs[0][kb + 1][srow] = b0.y;
    Bs[0][kb + 2][srow] = b0.z; Bs[0][kb + 3][srow] = b0.w;
    Bs[0][kb + 0][srow + 64] = b1.x; Bs[0][kb + 1][srow + 64] = b1.y;
    Bs[0][kb + 2][srow + 64] = b1.z; Bs[0][kb + 3][srow + 64] = b1.w;
  }
  __syncthreads();

  int cur = 0;
  for (int k0 = 0; k0 < K; k0 += 16) {
    bool more = (k0 + 16) < K;
    float4 na0, na1, nb0, nb1;
    if (more) {  // issue next-tile loads; they fly during the FMA block
      na0 = *(const float4*)(a0p + k0 + 16);
      na1 = *(const float4*)(a1p + k0 + 16);
      nb0 = v0 ? *(const float4*)(b0p + k0 + 16) : make_float4(0, 0, 0, 0);
      nb1 = v1 ? *(const float4*)(b1p + k0 + 16) : make_float4(0, 0, 0, 0);
    }
#pragma unroll
    for (int k = 0; k < 16; ++k) {
      float4 av0 = *(const float4*)&As[cur][k][ty * 4];       // 2-way: free
      float4 av1 = *(const float4*)&As[cur][k][ty * 4 + 64];
      float4 bv0 = *(const float4*)&Bs[cur][k][tx * 4];
      float4 bv1 = *(const float4*)&Bs[cur][k][tx * 4 + 64];
      float a[8] = {av0.x, av0.y, av0.z, av0.w, av1.x, av1.y, av1.z, av1.w};
      float b[8] = {bv0.x, bv0.y, bv0.z, bv0.w, bv1.x, bv1.y, bv1.z, bv1.w};
#pragma unroll
      for (int i = 0; i < 8; ++i)
#pragma unroll
        for (int j = 0; j < 8; ++j) acc[i][j] += a[i] * b[j];
    }
    if (more) {
      int nxt = cur ^ 1;  // write other buffer: no race with cur's readers
      As[nxt][kb + 0][srow] = na0.x; As[nxt][kb + 1][srow] = na0.y;
      As[nxt][kb + 2][srow] = na0.z; As[nxt][kb + 3][srow] = na0.w;
      As[nxt][kb + 0][srow + 64] = na1.x; As[nxt][kb + 1][srow + 64] = na1.y;
      As[nxt][kb + 2][srow + 64] = na1.z; As[nxt][kb + 3][srow + 64] = na1.w;
      Bs[nxt][kb + 0][srow] = nb0.x; Bs[nxt][kb + 1][srow] = nb0.y;
      Bs[nxt][kb + 2][srow] = nb0.z; Bs[nxt][kb + 3][srow] = nb0.w;
      Bs[nxt][kb + 0][srow + 64] = nb1.x; Bs[nxt][kb + 1][srow + 64] = nb1.y;
      Bs[nxt][kb + 2][srow + 64] = nb1.z; Bs[nxt][kb + 3][srow + 64] = nb1.w;
      __syncthreads();  // the only barrier per iteration
      cur = nxt;
    }
  }

  // Epilogue (split-fragment row/col mapping)
  float bsum[8];
#pragma unroll
  for (int j = 0; j < 8; ++j) {
    int n = n0 + (j < 4 ? tx * 4 + j : 64 + tx * 4 + (j - 4));
    bsum[j] = (n < Nvalid) ? (biasA[n] + (biasB ? biasB[n] : 0.0f)) : 0.0f;
  }
  if (xp_mode) {
    int dir = n0 >> 10;
    int nlo = (n0 & 1023) + tx * 4;
#pragma unroll
    for (int i = 0; i < 8; ++i) {
      int m = m0 + (i < 4 ? ty * 4 + i : 64 + ty * 4 + (i - 4));
      float* orow = out + ((size_t)dir * M + m) * 1024 + nlo;
      float4 r0 = make_float4(acc[i][0] + bsum[0], acc[i][1] + bsum[1],
                              acc[i][2] + bsum[2], acc[i][3] + bsum[3]);
      float4 r1 = make_float4(acc[i][4] + bsum[4], acc[i][5] + bsum[5],
                              acc[i][6] + bsum[6], acc[i][7] + bsum[7]);
      *(float4*)(orow) = r0;
      *(float4*)(orow + 64) = r1;
    }
  } else {
#pragma unroll
    for (int i = 0; i < 8; ++i) {
      int m = m0 + (i < 4 ? ty * 4 + i : 64 + ty * 4 + (i - 4));
#pragma unroll
      for (int j = 0; j < 8; ++j) {
        int n = n0 + (j < 4 ? tx * 4 + j : 64 + tx * 4 + (j - 4));
        if (n < Nvalid) out[(size_t)m * Nvalid + n] = acc[i][j] + bsum[j];
      }
    }
  }
}

// ---------------------------------------------------------------------------
// Register-stationary LSTM recurrence, v3.4b — EXACT r5/r8-verified state
// (~684us/dispatch).  Two barriers per step, single-buffer hS/xgS, simple
// spin, x-load at loop top (overlaps the spin — r6 proved moving it
// REGRESSES +40us; r1 proved barrier relaxation is catastrophic).
// Full-VALU DPP reduce + trans-pipe gates.
// DO NOT PERTURB: structure is at its exchange-latency floor.
// ---------------------------------------------------------------------------
__global__ __launch_bounds__(512) void lstm_fused3(
    const float* __restrict__ xp,    // [2][M][1024]
    const float* __restrict__ whh,   // [2][1024][256]
    const int* __restrict__ lengths,
    float* __restrict__ out,         // [M][512]
    unsigned long long* hx,          // [2 slot][2 d][16 bg][1024 packets]
    int T, int B) {
  __shared__ float4 hS[256];
  __shared__ float xgS[512];
  int blk = blockIdx.x;
  int js = blk >> 5;
  int inner = blk & 31;
  int d = inner >> 4;
  int bg = inner & 15;
  int tid = threadIdx.x;
  int jl = tid >> 4, kseg = tid & 15;
  int j = js * 32 + jl;
  size_t M = (size_t)T * B;
  int b0 = bg * 4;

  float w[4][16];
#pragma unroll
  for (int g = 0; g < 4; ++g) {
    const float* wr = whh + ((size_t)d * 1024 + g * 256 + j) * 256 + kseg;
#pragma unroll
    for (int i = 0; i < 16; ++i) w[g][i] = wr[16 * i];
  }

  int batch = b0 + (kseg & 3);
  int len = lengths[batch];
  float cst = 0.0f, hst = 0.0f;

  unsigned long long* hx_grp = hx + ((size_t)d * 16 + bg) * 1024;
  const size_t slotStride = (size_t)2 * 16 * 1024;

  int lb = tid >> 7, lg = (tid >> 5) & 3, lj = tid & 31;
  const float* xg_base = xp + (size_t)d * M * 1024 + (size_t)lg * 256 + js * 32 + lj;

  for (int s = 0; s < T; ++s) {
    int t = d ? (T - 1 - s) : s;
    float xv = xg_base[((size_t)t * B + b0 + lb) * 1024];
    if (s == 0) {
      if (tid < 256) hS[tid] = make_float4(0.f, 0.f, 0.f, 0.f);
    } else {
      const unsigned long long* src = hx_grp + (size_t)(s & 1) * slotStride;
      unsigned int want = (unsigned int)s;
      unsigned long long p0, p1;
      int guard = 0;
      for (;;) {
        p0 = __hip_atomic_load(src + tid, __ATOMIC_RELAXED, __HIP_MEMORY_SCOPE_AGENT);
        p1 = __hip_atomic_load(src + 512 + tid, __ATOMIC_RELAXED, __HIP_MEMORY_SCOPE_AGENT);
        if ((unsigned int)(p0 >> 32) == want && (unsigned int)(p1 >> 32) == want)
          break;
        if (++guard > (1 << 22)) break;  // hang-preventer
      }
      ((float*)hS)[tid] = __uint_as_float((unsigned int)p0);
      ((float*)hS)[512 + tid] = __uint_as_float((unsigned int)p1);
    }
    xgS[tid] = xv;
    __syncthreads();

    float acc[4][4];
#pragma unroll
    for (int g = 0; g < 4; ++g)
#pragma unroll
      for (int b = 0; b < 4; ++b) acc[g][b] = 0.0f;
#pragma unroll
    for (int i = 0; i < 16; ++i) {
      float4 hv = hS[kseg + 16 * i];
#pragma unroll
      for (int g = 0; g < 4; ++g) {
        acc[g][0] += w[g][i] * hv.x;
        acc[g][1] += w[g][i] * hv.y;
        acc[g][2] += w[g][i] * hv.z;
        acc[g][3] += w[g][i] * hv.w;
      }
    }
#pragma unroll
    for (int g = 0; g < 4; ++g)
#pragma unroll
      for (int b = 0; b < 4; ++b) {
        float v = acc[g][b];
        v = addx1(v);              // xor1 via DPP quad_perm
        v = addx2(v);              // xor2 via DPP quad_perm
        v = addror4(v);            // cross-quad stage 1 via DPP row_ror:4
        v = addror8(v);            // cross-quad stage 2 via DPP row_ror:8
        acc[g][b] = v;
      }

    if (kseg < 4) {
      int b = kseg;
      float ig = sigf(acc[0][b] + xgS[b * 128 + 0 * 32 + jl]);
      float fg = sigf(acc[1][b] + xgS[b * 128 + 1 * 32 + jl]);
      float gg = tanh_fast(acc[2][b] + xgS[b * 128 + 2 * 32 + jl]);
      float og = sigf(acc[3][b] + xgS[b * 128 + 3 * 32 + jl]);
      bool m = t < len;
      float cn = fg * cst + ig * gg;
      float hn = og * tanh_fast(cn);
      if (m) { cst = cn; hst = hn; }
      if (s + 1 < T) {
        unsigned long long pkt =
            ((unsigned long long)(unsigned int)(s + 1) << 32) | __float_as_uint(hst);
        unsigned long long* dst = hx_grp + (size_t)((s + 1) & 1) * slotStride +
                                  (size_t)js * 128 + jl * 4 + b;
        __hip_atomic_store(dst, pkt, __ATOMIC_RELAXED, __HIP_MEMORY_SCOPE_AGENT);
      }
      out[((size_t)t * B + batch) * 512 + d * 256 + j] = m ? hst : 0.0f;
    }
    __syncthreads();
  }
}

// ---------------------------------------------------------------------------
// Viterbi v4 (verified r5/r8): register trans column + even/odd dual-chain
// max with exact first-occurrence tie-break; LDS u8 hist backtrace. UNCHANGED.
// ---------------------------------------------------------------------------
__global__ __launch_bounds__(64) void viterbi_k(
    const float* __restrict__ em, const int* __restrict__ lengths,
    const float* __restrict__ startT, const float* __restrict__ endT,
    const float* __restrict__ trans,
    int* __restrict__ outTags, int T, int B) {
  __shared__ float sc[NTAG];
  __shared__ float ns[NTAG];
  __shared__ unsigned char histS[TT][NTAG];
  int b = blockIdx.x;
  int j = threadIdx.x;
  int len = lengths[b];
  float trc[NTAG];
  if (j < NTAG) {
#pragma unroll
    for (int i = 0; i < NTAG; ++i) trc[i] = trans[i * NTAG + j];
    sc[j] = startT[j] + em[(size_t)b * NTAG + j];
  }
  __syncthreads();
  for (int t = 1; t < T; ++t) {
    if (j < NTAG) {
      // two independent chains (even i / odd i), combined with first-
      // occurrence tie-break: winner by value, then by smaller index.
      float be = -3.0e38f, bo = -3.0e38f;
      int ae = 0, ao = 1;
#pragma unroll
      for (int i = 0; i < NTAG; i += 2) {
        float ve = sc[i] + trc[i];
        if (ve > be) { be = ve; ae = i; }
        float vo = sc[i + 1] + trc[i + 1];
        if (vo > bo) { bo = vo; ao = i + 1; }
      }
      float best; int arg;
      if (bo > be || (bo == be && ao < ae)) { best = bo; arg = ao; }
      else { best = be; arg = ae; }
      bool m = t < len;
      float e = em[((size_t)t * B + b) * NTAG + j];
      ns[j] = m ? (best + e) : sc[j];
      histS[t - 1][j] = (unsigned char)(m ? arg : j);
    }
    __syncthreads();
    if (j < NTAG) sc[j] = ns[j];
    __syncthreads();
  }
  if (j == 0) {
    float best = -3.0e38f;
    int arg = 0;
    for (int i = 0; i < NTAG; ++i) {
      float v = sc[i] + endT[i];
      if (v > best) { best = v; arg = i; }
    }
    int tag = arg;
    outTags[(size_t)(T - 1) * B + b] = (T - 1 < len) ? tag : 0;
    for (int t = T - 2; t >= 0; --t) {
      tag = histS[t][tag];
      outTags[(size_t)t * B + b] = (t < len) ? tag : 0;
    }
  }
}

extern "C" void kernel_launch(void* const* d_in, const int* in_sizes, int n_in,
                              void* d_out, int out_size, void* d_ws, size_t ws_size,
                              hipStream_t stream) {
  const int* x = (const int*)d_in[0];
  const int* lens = (const int*)d_in[1];
  const float* embed = (const float*)d_in[2];
  const float* w_ih0 = (const float*)d_in[3];
  const float* w_hh0 = (const float*)d_in[4];
  const float* b_ih0 = (const float*)d_in[5];
  const float* b_hh0 = (const float*)d_in[6];
  const float* w_ih1 = (const float*)d_in[7];
  const float* w_hh1 = (const float*)d_in[8];
  const float* b_ih1 = (const float*)d_in[9];
  const float* b_hh1 = (const float*)d_in[10];
  const float* w_lin = (const float*)d_in[11];
  const float* b_lin = (const float*)d_in[12];
  const float* startT = (const float*)d_in[13];
  const float* endT = (const float*)d_in[14];
  const float* trans = (const float*)d_in[15];
  int* outTags = (int*)d_out;

  const int T = TT, B = BB;
  const int M = T * B;

  char* ws = (char*)d_ws;
  const size_t SZ_XP = 2ull * M * 1024 * 4;
  const size_t SZ_H = (size_t)M * 512 * 4;
  const size_t SZ_EM = (size_t)M * NTAG * 4;
  const size_t SZ_HIST = (size_t)M * NTAG * 4;  // layout kept; hist in LDS
  float* xp = (float*)(ws);
  float* h0 = (float*)(ws + SZ_XP);
  float* h1 = (float*)(ws + SZ_XP + SZ_H);
  float* em = (float*)(ws + SZ_XP + 2 * SZ_H);
  unsigned long long* hx0 = (unsigned long long*)(ws + SZ_XP + 2 * SZ_H + SZ_EM + SZ_HIST);
  unsigned long long* hx1 = hx0 + 2ull * 2 * 16 * 1024;
  // No memset needed: 0xAA poison never matches a stamp value 1..255.

  // 1. Layer-0 input projection (fused embedding gather)
  gemm_k<<<dim3(M / 128, 16), 256, 0, stream>>>(embed, x, w_ih0, b_ih0, b_hh0,
                                                xp, M, 256, 2048, 1);
  // 2. Layer-0 recurrence
  lstm_fused3<<<256, 512, 0, stream>>>(xp, w_hh0, lens, h0, hx0, T, B);

  // 3. Layer-1 input projection
  gemm_k<<<dim3(M / 128, 16), 256, 0, stream>>>(h0, nullptr, w_ih1, b_ih1, b_hh1,
                                                xp, M, 512, 2048, 1);
  // 4. Layer-1 recurrence
  lstm_fused3<<<256, 512, 0, stream>>>(xp, w_hh1, lens, h1, hx1, T, B);

  // 5. Emissions
  gemm_k<<<dim3(M / 128, 1), 256, 0, stream>>>(h1, nullptr, w_lin, b_lin, nullptr,
                                               em, M, 512, 34, 0);
  // 6. Viterbi decode
  viterbi_k<<<64, 64, 0, stream>>>(em, lens, startT, endT, trans, outTags, T, B);
  (void)in_sizes; (void)n_in; (void)out_size; (void)ws_size;
}